// Round 5
// baseline (116.450 us; speedup 1.0000x reference)
//
#include <hip/hip_runtime.h>
#include <math.h>

// Problem constants (match reference)
#define Bn 2
#define Nn 512
#define Cn 151
#define Dn 4096
#define W_IMG 800.0f
#define H_IMG 600.0f
#define SCORE_T 0.05f
#define NMS_T 0.5f
#define TOPN 300
#define DETMAX 100
#define BBOX_CLAMP 4.135166556742356f   // log(1000/16)
#define NBLK 256                        // grid size; <= 256 CUs, all co-resident

// Output layout (float32, concatenated flat in reference return order)
#define OFF_BOXES  ((size_t)0)
#define OFF_SCORES ((size_t)(Bn * Nn * 4))            // 4096
#define OFF_LABELS (OFF_SCORES + (size_t)(Bn * Nn))   // 5120
#define OFF_VALID  (OFF_LABELS + (size_t)(Bn * Nn))   // 6144
#define OFF_FEATS  (OFF_VALID + (size_t)(Bn * Nn))    // 7168

// ---------------------------------------------------------------------------
// Inline box decode + clip (reference BoxCoder, TO_REMOVE=1, clip_to_image)
__device__ __forceinline__ float4 decode_clip(const float4 pr, const float4 rg) {
  const float w = pr.z - pr.x + 1.0f;
  const float h = pr.w - pr.y + 1.0f;
  const float cx = pr.x + 0.5f * w;
  const float cy = pr.y + 0.5f * h;
  const float dx = rg.x / 10.0f;
  const float dy = rg.y / 10.0f;
  const float dw = fminf(rg.z / 5.0f, BBOX_CLAMP);
  const float dh = fminf(rg.w / 5.0f, BBOX_CLAMP);
  const float pcx = dx * w + cx;
  const float pcy = dy * h + cy;
  const float pw = expf(dw) * w;
  const float ph = expf(dh) * h;
  float x1 = pcx - 0.5f * pw;
  float y1 = pcy - 0.5f * ph;
  float x2 = pcx + 0.5f * pw - 1.0f;
  float y2 = pcy + 0.5f * ph - 1.0f;
  x1 = fminf(fmaxf(x1, 0.0f), W_IMG - 1.0f);
  x2 = fminf(fmaxf(x2, 0.0f), W_IMG - 1.0f);
  y1 = fminf(fmaxf(y1, 0.0f), H_IMG - 1.0f);
  y2 = fminf(fmaxf(y2, 0.0f), H_IMG - 1.0f);
  return make_float4(x1, y1, x2, y2);
}

// ---------------------------------------------------------------------------
// Device-scope grid barrier — POLLS WITH RELAXED ATOMIC LOADS, not RMWs.
// (Round-4 lesson: atomicAdd(p,0) polling = serialized exclusive-ownership
// RMWs at the coherence point; ~30 us/barrier under 256-block contention.)
// Arrival slots padded to 64B (one line per block). Safe from 0xAA-poisoned
// state: phase tags {1,2} never equal the poison pattern and every slot is
// written with the current phase before being tested.
#define ASTRIDE 16   // 16 u32 = 64 B per arrival slot
__device__ __forceinline__ void grid_barrier(unsigned* arrive, unsigned* release,
                                             unsigned phase) {
  __syncthreads();
  if (threadIdx.x == 0) {
    __threadfence();                                  // release my writes
    __hip_atomic_store(&arrive[blockIdx.x * ASTRIDE], phase,
                       __ATOMIC_RELEASE, __HIP_MEMORY_SCOPE_AGENT);
  }
  if (blockIdx.x == 0) {
    unsigned* slot = &arrive[threadIdx.x * ASTRIDE];  // one slot per thread
    while (__hip_atomic_load(slot, __ATOMIC_RELAXED, __HIP_MEMORY_SCOPE_AGENT)
           != phase) __builtin_amdgcn_s_sleep(1);
    __syncthreads();
    if (threadIdx.x == 0)
      __hip_atomic_store(release, phase, __ATOMIC_RELEASE,
                         __HIP_MEMORY_SCOPE_AGENT);
  }
  if (threadIdx.x == 0) {
    while (__hip_atomic_load(release, __ATOMIC_RELAXED, __HIP_MEMORY_SCOPE_AGENT)
           != phase) __builtin_amdgcn_s_sleep(1);
    __threadfence();                                  // acquire others' writes
  }
  __syncthreads();
}

// ---------------------------------------------------------------------------
struct FallbackWS {          // phase-2 M>=64 cold path, one per active wave
  float fs[Nn];
  int   fn[Nn];
  float fb[Nn][4];
  unsigned char kp[Nn];
};
union SharedU {
  FallbackWS fwb[2];                                  // phase 2 (waves 0,1)
  struct { unsigned hist[256]; int red[256]; unsigned dsel[2]; } p3;  // phase 3
};

// ---------------------------------------------------------------------------
__global__ __launch_bounds__(256, 1) void fused_kernel(
    const float* __restrict__ logits, const float* __restrict__ reg,
    const float* __restrict__ props, const float* __restrict__ feats,
    float* __restrict__ out,
    unsigned long long* __restrict__ packed, float* __restrict__ prob_t,
    unsigned* arrive, unsigned* release) {
  __shared__ SharedU sh;
  __shared__ float thrS[Bn];
  const int blk = blockIdx.x;
  const int tid = threadIdx.x;
  const int wave = tid >> 6;
  const int lane = tid & 63;

  // ================= phase 1: softmax (one wave per proposal) ==============
  {
    const int bn = wave * NBLK + blk;                 // 0..1023
    const int b = bn >> 9;
    const int n = bn & (Nn - 1);
    const float* lrow = logits + (size_t)bn * Cn;
    const float l0 = lrow[lane];
    const float l1 = lrow[lane + 64];
    const float l2 = (lane + 128 < Cn) ? lrow[lane + 128] : -INFINITY;
    float mx = fmaxf(l0, fmaxf(l1, l2));
    #pragma unroll
    for (int o = 32; o > 0; o >>= 1) mx = fmaxf(mx, __shfl_xor(mx, o));
    const float e0 = expf(l0 - mx);
    const float e1 = expf(l1 - mx);
    const float e2 = (lane + 128 < Cn) ? expf(l2 - mx) : 0.0f;
    float sum = e0 + e1 + e2;
    #pragma unroll
    for (int o = 32; o > 0; o >>= 1) sum += __shfl_xor(sum, o);
    const float inv = 1.0f / sum;
    float* pt = prob_t + (size_t)b * Cn * Nn + n;     // transposed [B,C,N]
    pt[(size_t)lane * Nn] = e0 * inv;
    pt[(size_t)(lane + 64) * Nn] = e1 * inv;
    if (lane + 128 < Cn) pt[(size_t)(lane + 128) * Nn] = e2 * inv;
    if (lane == 0) packed[bn] = 0ull;
  }
  grid_barrier(arrive, release, 1u);

  // ================= phase 2: per-(b,c) NMS (one wave per class) ===========
  {
    const int bc = wave * NBLK + blk;                 // waves 0,1 cover 302
    if (bc < Bn * Cn && (bc % Cn) != 0) {             // skip background c=0
      const int b = bc / Cn;
      const int c = bc % Cn;
      const float* col = prob_t + ((size_t)b * Cn + c) * Nn;

      // compact valid (score>T) items into lanes [0,M) via ds_permute push
      float s_acc = -1.0f; int n_acc = -1;
      int base = 0;
      #pragma unroll
      for (int j = 0; j < Nn / 64; ++j) {
        const int n = j * 64 + lane;
        const float sv = col[n];
        const bool v = sv > SCORE_T;
        const unsigned long long m = __ballot(v);
        const int cnt = __popcll(m);
        if (cnt) {
          const int pos = base + __popcll(m & ((1ull << lane) - 1ull));
          const int dest = v ? (pos & 63) : 63;       // invalid lanes park @63
          const int rs = __builtin_amdgcn_ds_permute(dest << 2, __float_as_int(sv));
          const int rn = __builtin_amdgcn_ds_permute(dest << 2, n);
          if (lane >= base && lane < base + cnt) { s_acc = __int_as_float(rs); n_acc = rn; }
          base += cnt;
        }
      }
      const int M = base;

      if (M > 0 && M < 64) {
        // ---- register fast path: rank sort + ballot NMS ----
        const float s = s_acc; const int n = n_acc;   // invalid lanes: (-1,-1)
        int rank = 0;
        for (int j = 0; j < M; ++j) {
          const float sj = __shfl(s, j);
          const int nj = __shfl(n, j);
          rank += ((sj > s) || (sj == s && nj < n)) ? 1 : 0;
        }                                              // invalid lanes -> rank==M
        const int rs2 = __builtin_amdgcn_ds_permute((rank & 63) << 2, __float_as_int(s));
        const int rn2 = __builtin_amdgcn_ds_permute((rank & 63) << 2, n);
        const float sc = __int_as_float(rs2);
        const int sn = rn2;
        float x1 = 0.0f, y1 = 0.0f, x2 = 0.0f, y2 = 0.0f;
        if (lane < M) {
          const int i = b * Nn + sn;
          const float4 pr = ((const float4*)props)[i];
          const float4 rg = ((const float4*)reg)[(size_t)i * Cn + c];
          const float4 bx = decode_clip(pr, rg);
          x1 = bx.x; y1 = bx.y; x2 = bx.z; y2 = bx.w;
        }
        const float area = (x2 - x1 + 1.0f) * (y2 - y1 + 1.0f);
        unsigned long long live = (1ull << M) - 1ull;
        int i = 0;
        while (i < 64) {
          const unsigned long long rem = live & (~0ull << i);
          if (!rem) break;
          i = __ffsll(rem) - 1;
          const float ax1 = __shfl(x1, i), ay1 = __shfl(y1, i);
          const float ax2 = __shfl(x2, i), ay2 = __shfl(y2, i);
          const float aarea = (ax2 - ax1 + 1.0f) * (ay2 - ay1 + 1.0f);
          const float xx1 = fmaxf(ax1, x1), yy1 = fmaxf(ay1, y1);
          const float xx2 = fminf(ax2, x2), yy2 = fminf(ay2, y2);
          const float inter = fmaxf(xx2 - xx1 + 1.0f, 0.0f) * fmaxf(yy2 - yy1 + 1.0f, 0.0f);
          const float iou = inter / (aarea + area - inter);
          const bool sup = (lane > i) && (lane < M) && ((live >> lane) & 1ull) && (iou > NMS_T);
          live &= ~__ballot(sup);
          ++i;
        }
        // M < 64 < TOPN: per-class top-300 can't bind
        if (lane < M && ((live >> lane) & 1ull)) {
          const unsigned long long key =
              ((unsigned long long)__float_as_uint(sc) << 32) | (unsigned int)(Cn - c);
          atomicMax(&packed[(size_t)b * Nn + sn], key);
        }
      } else if (M >= 64) {
        // ---- exact wave-local LDS fallback (improbable) ----
        FallbackWS* W = &sh.fwb[wave];                // wave is 0 or 1 here
        int b2 = 0;
        for (int j = 0; j < Nn / 64; ++j) {
          const int n = j * 64 + lane;
          const float sv = col[n];
          const bool v = sv > SCORE_T;
          const unsigned long long m = __ballot(v);
          if (v) {
            const int pos = b2 + __popcll(m & ((1ull << lane) - 1ull));
            W->fb[pos][0] = sv;
            W->fb[pos][1] = __int_as_float(n);
          }
          b2 += __popcll(m);
        }
        __threadfence_block();
        for (int i0 = lane; i0 < M; i0 += 64) {
          const float si = W->fb[i0][0]; const int ni = __float_as_int(W->fb[i0][1]);
          int r = 0;
          for (int j = 0; j < M; ++j) {
            const float sj = W->fb[j][0]; const int nj = __float_as_int(W->fb[j][1]);
            r += ((sj > si) || (sj == si && nj < ni)) ? 1 : 0;
          }
          W->fs[r] = si; W->fn[r] = ni;
        }
        __threadfence_block();
        for (int i0 = lane; i0 < M; i0 += 64) {
          const int i = b * Nn + W->fn[i0];
          const float4 pr = ((const float4*)props)[i];
          const float4 rg = ((const float4*)reg)[(size_t)i * Cn + c];
          const float4 bx = decode_clip(pr, rg);
          W->fb[i0][0] = bx.x; W->fb[i0][1] = bx.y; W->fb[i0][2] = bx.z; W->fb[i0][3] = bx.w;
          W->kp[i0] = 1;
        }
        __threadfence_block();
        for (int i = 0; i < M; ++i) {
          if (!W->kp[i]) continue;                    // wave-uniform
          const float ax1 = W->fb[i][0], ay1 = W->fb[i][1];
          const float ax2 = W->fb[i][2], ay2 = W->fb[i][3];
          const float aarea = (ax2 - ax1 + 1.0f) * (ay2 - ay1 + 1.0f);
          for (int t = i + 1 + lane; t < M; t += 64) {
            if (W->kp[t]) {
              const float bx1 = W->fb[t][0], by1 = W->fb[t][1];
              const float bx2 = W->fb[t][2], by2 = W->fb[t][3];
              const float barea = (bx2 - bx1 + 1.0f) * (by2 - by1 + 1.0f);
              const float xx1 = fmaxf(ax1, bx1), yy1 = fmaxf(ay1, by1);
              const float xx2 = fminf(ax2, bx2), yy2 = fminf(ay2, by2);
              const float inter = fmaxf(xx2 - xx1 + 1.0f, 0.0f) * fmaxf(yy2 - yy1 + 1.0f, 0.0f);
              if (inter / (aarea + barea - inter) > NMS_T) W->kp[t] = 0;
            }
          }
          __threadfence_block();
        }
        if (lane == 0) {
          int cnt = 0;
          for (int t = 0; t < M; ++t)
            if (W->kp[t]) { if (++cnt > TOPN) W->kp[t] = 0; }
        }
        __threadfence_block();
        for (int t = lane; t < M; t += 64) {
          if (W->kp[t]) {
            const unsigned long long key =
                ((unsigned long long)__float_as_uint(W->fs[t]) << 32) | (unsigned int)(Cn - c);
            atomicMax(&packed[(size_t)b * Nn + W->fn[t]], key);
          }
        }
      }
    }
  }
  grid_barrier(arrive, release, 2u);

  // ===== phase 3: per-image top-100 threshold — REDUNDANT in every block ===
  // (saves a grid barrier: each block computes both images' thresholds from
  //  packed[] into LDS; ~8 KB reads, L2/L3-served)
  for (int b = 0; b < Bn; ++b) {
    const unsigned k0 = (unsigned)(packed[(size_t)b * Nn + tid] >> 32);
    const unsigned k1 = (unsigned)(packed[(size_t)b * Nn + 256 + tid] >> 32);
    sh.p3.red[tid] = (k0 ? 1 : 0) + (k1 ? 1 : 0);
    __syncthreads();
    for (int s2 = 128; s2 > 0; s2 >>= 1) {
      if (tid < s2) sh.p3.red[tid] += sh.p3.red[tid + s2];
      __syncthreads();
    }
    const int num = sh.p3.red[0];
    __syncthreads();
    float tv = -1.0f;
    if (num > DETMAX) {                               // block-uniform branch
      unsigned prefix = 0;
      unsigned want = DETMAX;                         // rank from the top
      for (int shift = 24; shift >= 0; shift -= 8) {
        sh.p3.hist[tid] = 0;
        __syncthreads();
        const unsigned hm = (shift < 24) ? (0xFFFFFFFFu << (shift + 8)) : 0u;
        if (k0 && (k0 & hm) == (prefix & hm)) atomicAdd(&sh.p3.hist[(k0 >> shift) & 0xFF], 1u);
        if (k1 && (k1 & hm) == (prefix & hm)) atomicAdd(&sh.p3.hist[(k1 >> shift) & 0xFF], 1u);
        __syncthreads();
        if (tid < 64) {                               // wave 0: find the digit
          const int l = tid;
          const unsigned h0 = sh.p3.hist[4 * l], h1 = sh.p3.hist[4 * l + 1];
          const unsigned h2 = sh.p3.hist[4 * l + 2], h3 = sh.p3.hist[4 * l + 3];
          const unsigned chunk = h0 + h1 + h2 + h3;
          unsigned suf = chunk;                       // sum over lanes >= l
          #pragma unroll
          for (int off = 1; off < 64; off <<= 1) {
            const unsigned t2 = __shfl_down(suf, off);
            if (l + off < 64) suf += t2;
          }
          const unsigned g3 = suf - chunk;            // count digits > 4l+3
          const unsigned g2 = g3 + h3;
          const unsigned g1 = g2 + h2;
          const unsigned g0 = g1 + h1;
          if (g3 < want && want <= g3 + h3) { sh.p3.dsel[0] = 4 * l + 3; sh.p3.dsel[1] = want - g3; }
          if (g2 < want && want <= g2 + h2) { sh.p3.dsel[0] = 4 * l + 2; sh.p3.dsel[1] = want - g2; }
          if (g1 < want && want <= g1 + h1) { sh.p3.dsel[0] = 4 * l + 1; sh.p3.dsel[1] = want - g1; }
          if (g0 < want && want <= g0 + h0) { sh.p3.dsel[0] = 4 * l + 0; sh.p3.dsel[1] = want - g0; }
        }
        __syncthreads();
        prefix |= sh.p3.dsel[0] << shift;
        want = sh.p3.dsel[1];
        __syncthreads();
      }
      tv = __uint_as_float(prefix);                   // exact 100th-largest
    }
    if (tid == 0) thrS[b] = tv;
    __syncthreads();
  }

  // ================= phase 4: outputs + feature masking (one wave/row) =====
  {
    const int row = blk * 4 + wave;                   // 0..1023
    const int b = row >> 9;
    const unsigned long long p = packed[row];
    const float s = __uint_as_float((unsigned)(p >> 32));
    const int label = (p != 0ull) ? (Cn - (int)(p & 0xFFFFFFFFull)) : 0;
    const bool valid = (s > 0.0f) && (s >= thrS[b]);
    if (lane == 0) {
      float4 ob = make_float4(0.0f, 0.0f, 0.0f, 0.0f);
      if (valid) {
        const float4 pr = ((const float4*)props)[row];
        const float4 rg = ((const float4*)reg)[(size_t)row * Cn + label];
        ob = decode_clip(pr, rg);
      }
      ((float4*)(out + OFF_BOXES))[row] = ob;
      out[OFF_SCORES + row] = valid ? s : 0.0f;
      out[OFF_LABELS + row] = valid ? (float)label : 0.0f;
      out[OFF_VALID + row] = valid ? 1.0f : 0.0f;
    }
    const float mval = valid ? 1.0f : 0.0f;
    const float4* fi = (const float4*)(feats + (size_t)row * Dn);
    float4* fo = (float4*)(out + OFF_FEATS + (size_t)row * Dn);
    #pragma unroll
    for (int i = 0; i < Dn / 4 / 64; ++i) {
      float4 x = fi[i * 64 + lane];
      x.x *= mval; x.y *= mval; x.z *= mval; x.w *= mval;
      fo[i * 64 + lane] = x;
    }
  }
}

// ---------------------------------------------------------------------------
extern "C" void kernel_launch(void* const* d_in, const int* in_sizes, int n_in,
                              void* d_out, int out_size, void* d_ws, size_t ws_size,
                              hipStream_t stream) {
  const float* logits = (const float*)d_in[0];   // [B,N,C]
  const float* reg    = (const float*)d_in[1];   // [B,N,C*4]
  const float* props  = (const float*)d_in[2];   // [B,N,4]
  const float* feats  = (const float*)d_in[3];   // [B,N,D]
  float* out = (float*)d_out;

  // workspace carve-up (packed first for 8B alignment)
  unsigned long long* packed = (unsigned long long*)d_ws;        // B*N
  float* prob_t = (float*)(packed + Bn * Nn);                    // B*C*N
  unsigned* arrive = (unsigned*)(prob_t + (size_t)Bn * Cn * Nn); // NBLK*ASTRIDE
  unsigned* release = arrive + NBLK * ASTRIDE;                   // 1

  fused_kernel<<<NBLK, 256, 0, stream>>>(logits, reg, props, feats, out,
                                         packed, prob_t, arrive, release);
}

// Round 6
// 91.997 us; speedup vs baseline: 1.2658x; 1.2658x over previous
//
#include <hip/hip_runtime.h>
#include <math.h>

// Problem constants (match reference)
#define Bn 2
#define Nn 512
#define Cn 151
#define Dn 4096
#define W_IMG 800.0f
#define H_IMG 600.0f
#define SCORE_T 0.05f
#define NMS_T 0.5f
#define TOPN 300
#define DETMAX 100
#define BBOX_CLAMP 4.135166556742356f   // log(1000/16)

// Output layout (float32, concatenated flat in reference return order)
#define OFF_BOXES  ((size_t)0)
#define OFF_SCORES ((size_t)(Bn * Nn * 4))            // 4096
#define OFF_LABELS (OFF_SCORES + (size_t)(Bn * Nn))   // 5120
#define OFF_VALID  (OFF_LABELS + (size_t)(Bn * Nn))   // 6144
#define OFF_FEATS  (OFF_VALID + (size_t)(Bn * Nn))    // 7168

// Round-5 lesson (measured): a device-scope grid barrier costs ~15-17 us at
// 256 blocks (regardless of RMW vs load polling) -> persistent-kernel fusion
// loses to 3 separate graph-replayed launches (~2 us each). Multi-kernel it is.

// ---------------------------------------------------------------------------
// Inline box decode + clip (reference BoxCoder, TO_REMOVE=1, clip_to_image)
__device__ __forceinline__ float4 decode_clip(const float4 pr, const float4 rg) {
  const float w = pr.z - pr.x + 1.0f;
  const float h = pr.w - pr.y + 1.0f;
  const float cx = pr.x + 0.5f * w;
  const float cy = pr.y + 0.5f * h;
  const float dx = rg.x / 10.0f;
  const float dy = rg.y / 10.0f;
  const float dw = fminf(rg.z / 5.0f, BBOX_CLAMP);
  const float dh = fminf(rg.w / 5.0f, BBOX_CLAMP);
  const float pcx = dx * w + cx;
  const float pcy = dy * h + cy;
  const float pw = expf(dw) * w;
  const float ph = expf(dh) * h;
  float x1 = pcx - 0.5f * pw;
  float y1 = pcy - 0.5f * ph;
  float x2 = pcx + 0.5f * pw - 1.0f;
  float y2 = pcy + 0.5f * ph - 1.0f;
  x1 = fminf(fmaxf(x1, 0.0f), W_IMG - 1.0f);
  x2 = fminf(fmaxf(x2, 0.0f), W_IMG - 1.0f);
  y1 = fminf(fmaxf(y1, 0.0f), H_IMG - 1.0f);
  y2 = fminf(fmaxf(y2, 0.0f), H_IMG - 1.0f);
  return make_float4(x1, y1, x2, y2);
}

// ---------------------------------------------------------------------------
// k_stats: one wave per proposal. Per-row softmax stats (max, 1/expsum) only —
// no prob matrix materialized. Reduction structure identical to the passing
// rounds, so downstream scores are bit-identical. Also zeroes packed[].
__global__ __launch_bounds__(256) void k_stats(const float* __restrict__ logits,
                                               float* __restrict__ mxA,
                                               float* __restrict__ invA,
                                               unsigned long long* __restrict__ packed) {
  const int wave = threadIdx.x >> 6;
  const int lane = threadIdx.x & 63;
  const int bn = wave * 256 + blockIdx.x;             // 0..1023 (same map as r5)
  const float* lrow = logits + (size_t)bn * Cn;
  const float l0 = lrow[lane];
  const float l1 = lrow[lane + 64];
  const float l2 = (lane + 128 < Cn) ? lrow[lane + 128] : -INFINITY;
  float mx = fmaxf(l0, fmaxf(l1, l2));
  #pragma unroll
  for (int o = 32; o > 0; o >>= 1) mx = fmaxf(mx, __shfl_xor(mx, o));
  const float e0 = expf(l0 - mx);
  const float e1 = expf(l1 - mx);
  const float e2 = (lane + 128 < Cn) ? expf(l2 - mx) : 0.0f;
  float sum = e0 + e1 + e2;
  #pragma unroll
  for (int o = 32; o > 0; o >>= 1) sum += __shfl_xor(sum, o);
  if (lane == 0) {
    mxA[bn] = mx;
    invA[bn] = 1.0f / sum;
    packed[bn] = 0ull;
  }
}

// ---------------------------------------------------------------------------
struct FallbackWS {          // NMS M>=64 cold path, one per wave
  float fs[Nn];
  int   fn[Nn];
  float fb[Nn][4];
  unsigned char kp[Nn];
};

// k_nms: one wave per (b,c). Scores computed on the fly from logits + stats
// (bit-identical to materialized prob). Compact valid (>T) via ballot +
// ds_permute, register rank sort, ballot greedy NMS; atomicMax packed key
// (score_bits<<32 | Cn-c) -> per-proposal argmax, first-index tiebreak.
__global__ __launch_bounds__(256) void k_nms(const float* __restrict__ logits,
                                             const float* __restrict__ mxA,
                                             const float* __restrict__ invA,
                                             const float* __restrict__ reg,
                                             const float* __restrict__ props,
                                             unsigned long long* __restrict__ packed) {
  __shared__ FallbackWS fwb[4];
  const int wave = threadIdx.x >> 6;
  const int lane = threadIdx.x & 63;
  const int bc = blockIdx.x * 4 + wave;
  if (bc >= Bn * Cn) return;
  const int b = bc / Cn;
  const int c = bc % Cn;
  if (c == 0) return;                                 // background dropped

  const float* lcol = logits + (size_t)b * Nn * Cn + c;   // stride Cn
  const float* mxB = mxA + b * Nn;
  const float* invB = invA + b * Nn;

  // compact valid (score>T) items into lanes [0,M) via ds_permute push
  float s_acc = -1.0f; int n_acc = -1;
  int base = 0;
  #pragma unroll
  for (int j = 0; j < Nn / 64; ++j) {
    const int n = j * 64 + lane;
    const float sv = expf(lcol[(size_t)n * Cn] - mxB[n]) * invB[n];
    const bool v = sv > SCORE_T;
    const unsigned long long m = __ballot(v);
    const int cnt = __popcll(m);
    if (cnt) {
      const int pos = base + __popcll(m & ((1ull << lane) - 1ull));
      const int dest = v ? (pos & 63) : 63;           // invalid lanes park @63
      const int rs = __builtin_amdgcn_ds_permute(dest << 2, __float_as_int(sv));
      const int rn = __builtin_amdgcn_ds_permute(dest << 2, n);
      if (lane >= base && lane < base + cnt) { s_acc = __int_as_float(rs); n_acc = rn; }
      base += cnt;
    }
  }
  const int M = base;

  if (M > 0 && M < 64) {
    // ---- register fast path: rank sort + ballot NMS ----
    const float s = s_acc; const int n = n_acc;       // invalid lanes: (-1,-1)
    int rank = 0;
    for (int j = 0; j < M; ++j) {
      const float sj = __shfl(s, j);
      const int nj = __shfl(n, j);
      rank += ((sj > s) || (sj == s && nj < n)) ? 1 : 0;
    }                                                  // invalid lanes -> rank==M
    const int rs2 = __builtin_amdgcn_ds_permute((rank & 63) << 2, __float_as_int(s));
    const int rn2 = __builtin_amdgcn_ds_permute((rank & 63) << 2, n);
    const float sc = __int_as_float(rs2);
    const int sn = rn2;
    float x1 = 0.0f, y1 = 0.0f, x2 = 0.0f, y2 = 0.0f;
    if (lane < M) {
      const int i = b * Nn + sn;
      const float4 pr = ((const float4*)props)[i];
      const float4 rg = ((const float4*)reg)[(size_t)i * Cn + c];
      const float4 bx = decode_clip(pr, rg);
      x1 = bx.x; y1 = bx.y; x2 = bx.z; y2 = bx.w;
    }
    const float area = (x2 - x1 + 1.0f) * (y2 - y1 + 1.0f);
    unsigned long long live = (1ull << M) - 1ull;
    int i = 0;
    while (i < 64) {
      const unsigned long long rem = live & (~0ull << i);
      if (!rem) break;
      i = __ffsll(rem) - 1;
      const float ax1 = __shfl(x1, i), ay1 = __shfl(y1, i);
      const float ax2 = __shfl(x2, i), ay2 = __shfl(y2, i);
      const float aarea = (ax2 - ax1 + 1.0f) * (ay2 - ay1 + 1.0f);
      const float xx1 = fmaxf(ax1, x1), yy1 = fmaxf(ay1, y1);
      const float xx2 = fminf(ax2, x2), yy2 = fminf(ay2, y2);
      const float inter = fmaxf(xx2 - xx1 + 1.0f, 0.0f) * fmaxf(yy2 - yy1 + 1.0f, 0.0f);
      const float iou = inter / (aarea + area - inter);
      const bool sup = (lane > i) && (lane < M) && ((live >> lane) & 1ull) && (iou > NMS_T);
      live &= ~__ballot(sup);
      ++i;
    }
    // M < 64 < TOPN: per-class top-300 can't bind
    if (lane < M && ((live >> lane) & 1ull)) {
      const unsigned long long key =
          ((unsigned long long)__float_as_uint(sc) << 32) | (unsigned int)(Cn - c);
      atomicMax(&packed[(size_t)b * Nn + sn], key);
    }
  } else if (M >= 64) {
    // ---- exact wave-local LDS fallback (improbable). Wave-local only:
    // __threadfence_block = fence, not barrier -> divergence-safe.
    FallbackWS* W = &fwb[wave];
    int b2 = 0;
    for (int j = 0; j < Nn / 64; ++j) {
      const int n = j * 64 + lane;
      const float sv = expf(lcol[(size_t)n * Cn] - mxB[n]) * invB[n];
      const bool v = sv > SCORE_T;
      const unsigned long long m = __ballot(v);
      if (v) {
        const int pos = b2 + __popcll(m & ((1ull << lane) - 1ull));
        W->fb[pos][0] = sv;
        W->fb[pos][1] = __int_as_float(n);
      }
      b2 += __popcll(m);
    }
    __threadfence_block();
    for (int i0 = lane; i0 < M; i0 += 64) {
      const float si = W->fb[i0][0]; const int ni = __float_as_int(W->fb[i0][1]);
      int r = 0;
      for (int j = 0; j < M; ++j) {
        const float sj = W->fb[j][0]; const int nj = __float_as_int(W->fb[j][1]);
        r += ((sj > si) || (sj == si && nj < ni)) ? 1 : 0;
      }
      W->fs[r] = si; W->fn[r] = ni;
    }
    __threadfence_block();
    for (int i0 = lane; i0 < M; i0 += 64) {
      const int i = b * Nn + W->fn[i0];
      const float4 pr = ((const float4*)props)[i];
      const float4 rg = ((const float4*)reg)[(size_t)i * Cn + c];
      const float4 bx = decode_clip(pr, rg);
      W->fb[i0][0] = bx.x; W->fb[i0][1] = bx.y; W->fb[i0][2] = bx.z; W->fb[i0][3] = bx.w;
      W->kp[i0] = 1;
    }
    __threadfence_block();
    for (int i = 0; i < M; ++i) {
      if (!W->kp[i]) continue;                        // wave-uniform
      const float ax1 = W->fb[i][0], ay1 = W->fb[i][1];
      const float ax2 = W->fb[i][2], ay2 = W->fb[i][3];
      const float aarea = (ax2 - ax1 + 1.0f) * (ay2 - ay1 + 1.0f);
      for (int t = i + 1 + lane; t < M; t += 64) {
        if (W->kp[t]) {
          const float bx1 = W->fb[t][0], by1 = W->fb[t][1];
          const float bx2 = W->fb[t][2], by2 = W->fb[t][3];
          const float barea = (bx2 - bx1 + 1.0f) * (by2 - by1 + 1.0f);
          const float xx1 = fmaxf(ax1, bx1), yy1 = fmaxf(ay1, by1);
          const float xx2 = fminf(ax2, bx2), yy2 = fminf(ay2, by2);
          const float inter = fmaxf(xx2 - xx1 + 1.0f, 0.0f) * fmaxf(yy2 - yy1 + 1.0f, 0.0f);
          if (inter / (aarea + barea - inter) > NMS_T) W->kp[t] = 0;
        }
      }
      __threadfence_block();
    }
    if (lane == 0) {
      int cnt = 0;
      for (int t = 0; t < M; ++t)
        if (W->kp[t]) { if (++cnt > TOPN) W->kp[t] = 0; }
    }
    __threadfence_block();
    for (int t = lane; t < M; t += 64) {
      if (W->kp[t]) {
        const unsigned long long key =
            ((unsigned long long)__float_as_uint(W->fs[t]) << 32) | (unsigned int)(Cn - c);
        atomicMax(&packed[(size_t)b * Nn + W->fn[t]], key);
      }
    }
  }
}

// ---------------------------------------------------------------------------
// k_final: 256 blocks x 256. Each block redundantly computes ITS image's
// top-100 threshold from packed (8 KB read, 4-pass radix select), then
// handles 4 rows (one wave per row): unpack (score,label), decode winner box,
// write outputs, mask features (feats read skipped for invalid rows).
__global__ __launch_bounds__(256) void k_final(const unsigned long long* __restrict__ packed,
                                               const float* __restrict__ reg,
                                               const float* __restrict__ props,
                                               const float* __restrict__ feats,
                                               float* __restrict__ out) {
  __shared__ unsigned hist[256];
  __shared__ int red[256];
  __shared__ unsigned dsel[2];
  __shared__ float thrS;
  const int blk = blockIdx.x;
  const int tid = threadIdx.x;
  const int wave = tid >> 6;
  const int lane = tid & 63;
  const int b = blk >> 7;                             // rows blk*4.. are in image b

  // ---- per-image top-100 threshold (redundant per block) ----
  const unsigned k0 = (unsigned)(packed[(size_t)b * Nn + tid] >> 32);
  const unsigned k1 = (unsigned)(packed[(size_t)b * Nn + 256 + tid] >> 32);
  red[tid] = (k0 ? 1 : 0) + (k1 ? 1 : 0);
  __syncthreads();
  for (int s2 = 128; s2 > 0; s2 >>= 1) {
    if (tid < s2) red[tid] += red[tid + s2];
    __syncthreads();
  }
  const int num = red[0];
  float tv = -1.0f;
  if (num > DETMAX) {                                 // block-uniform branch
    unsigned prefix = 0;
    unsigned want = DETMAX;                           // rank from the top
    for (int shift = 24; shift >= 0; shift -= 8) {
      hist[tid] = 0;
      __syncthreads();
      const unsigned hm = (shift < 24) ? (0xFFFFFFFFu << (shift + 8)) : 0u;
      if (k0 && (k0 & hm) == (prefix & hm)) atomicAdd(&hist[(k0 >> shift) & 0xFF], 1u);
      if (k1 && (k1 & hm) == (prefix & hm)) atomicAdd(&hist[(k1 >> shift) & 0xFF], 1u);
      __syncthreads();
      if (tid < 64) {                                 // wave 0: locate the digit
        const int l = tid;
        const unsigned h0 = hist[4 * l], h1 = hist[4 * l + 1];
        const unsigned h2 = hist[4 * l + 2], h3 = hist[4 * l + 3];
        const unsigned chunk = h0 + h1 + h2 + h3;
        unsigned suf = chunk;                         // sum over lanes >= l
        #pragma unroll
        for (int off = 1; off < 64; off <<= 1) {
          const unsigned t2 = __shfl_down(suf, off);
          if (l + off < 64) suf += t2;
        }
        const unsigned g3 = suf - chunk;              // count digits > 4l+3
        const unsigned g2 = g3 + h3;
        const unsigned g1 = g2 + h2;
        const unsigned g0 = g1 + h1;
        if (g3 < want && want <= g3 + h3) { dsel[0] = 4 * l + 3; dsel[1] = want - g3; }
        if (g2 < want && want <= g2 + h2) { dsel[0] = 4 * l + 2; dsel[1] = want - g2; }
        if (g1 < want && want <= g1 + h1) { dsel[0] = 4 * l + 1; dsel[1] = want - g1; }
        if (g0 < want && want <= g0 + h0) { dsel[0] = 4 * l + 0; dsel[1] = want - g0; }
      }
      __syncthreads();
      prefix |= dsel[0] << shift;
      want = dsel[1];
      __syncthreads();
    }
    tv = __uint_as_float(prefix);                     // exact 100th-largest
  }
  if (tid == 0) thrS = tv;
  __syncthreads();

  // ---- outputs + feature masking (one wave per row) ----
  const int row = blk * 4 + wave;                     // 0..1023, row>>9 == b
  const unsigned long long p = packed[row];
  const float s = __uint_as_float((unsigned)(p >> 32));
  const int label = (p != 0ull) ? (Cn - (int)(p & 0xFFFFFFFFull)) : 0;
  const bool valid = (s > 0.0f) && (s >= thrS);
  if (lane == 0) {
    float4 ob = make_float4(0.0f, 0.0f, 0.0f, 0.0f);
    if (valid) {
      const float4 pr = ((const float4*)props)[row];
      const float4 rg = ((const float4*)reg)[(size_t)row * Cn + label];
      ob = decode_clip(pr, rg);
    }
    ((float4*)(out + OFF_BOXES))[row] = ob;
    out[OFF_SCORES + row] = valid ? s : 0.0f;
    out[OFF_LABELS + row] = valid ? (float)label : 0.0f;
    out[OFF_VALID + row] = valid ? 1.0f : 0.0f;
  }
  float4* fo = (float4*)(out + OFF_FEATS + (size_t)row * Dn);
  if (valid) {                                        // wave-uniform branch
    const float4* fi = (const float4*)(feats + (size_t)row * Dn);
    #pragma unroll
    for (int i = 0; i < Dn / 4 / 64; ++i) fo[i * 64 + lane] = fi[i * 64 + lane];
  } else {                                            // skip the 16 KB read
    const float4 z = make_float4(0.0f, 0.0f, 0.0f, 0.0f);
    #pragma unroll
    for (int i = 0; i < Dn / 4 / 64; ++i) fo[i * 64 + lane] = z;
  }
}

// ---------------------------------------------------------------------------
extern "C" void kernel_launch(void* const* d_in, const int* in_sizes, int n_in,
                              void* d_out, int out_size, void* d_ws, size_t ws_size,
                              hipStream_t stream) {
  const float* logits = (const float*)d_in[0];   // [B,N,C]
  const float* reg    = (const float*)d_in[1];   // [B,N,C*4]
  const float* props  = (const float*)d_in[2];   // [B,N,4]
  const float* feats  = (const float*)d_in[3];   // [B,N,D]
  float* out = (float*)d_out;

  // workspace carve-up (packed first for 8B alignment)
  unsigned long long* packed = (unsigned long long*)d_ws;   // B*N
  float* mxA  = (float*)(packed + Bn * Nn);                 // B*N
  float* invA = mxA + Bn * Nn;                              // B*N

  k_stats<<<256, 256, 0, stream>>>(logits, mxA, invA, packed);
  k_nms<<<(Bn * Cn + 3) / 4, 256, 0, stream>>>(logits, mxA, invA, reg, props, packed);
  k_final<<<256, 256, 0, stream>>>(packed, reg, props, feats, out);
}